// Round 4
// baseline (512.049 us; speedup 1.0000x reference)
//
#include <hip/hip_runtime.h>

// Spatial LRN: out = x / (2 + 1e-4 * ssq)^0.75, ssq = 5x5 box sum of x^2 (zero pad 2).
// x: (16, 96, 224, 224) fp32.
//
// Round-4 structure: straight-line burst (R3) + 1-load-per-row via shfl + high
// occupancy. R3 loaded each 16B 3x (xl/xc/xr): 36 loads/job = 144 VGPR of load
// destinations -> compiler batched loads ~9 at a time with near-full drains,
// occupancy stuck at 4 waves/SIMD. Here each lane loads its own float4 ONCE per
// row; horizontal neighbor taps are 4 __shfl of the squared values (straight-
// line, fully unrolled, no carried chain -> DS pipelines under VALU). 4 output
// rows per job (8 input rows): X[8]=32 + acc[4]=16 VGPR -> ~70 live, cap 84 via
// __launch_bounds__(256,6) => >=6 waves/SIMD (vs 4), 8 KB/wave in flight.
// Halo re-reads (8 in-rows per 4 out-rows) are L2-hits: consecutive jobs are
// vertically adjacent slabs of the same plane, co-resident in dispatch order.
//
// Lane q owns float4 column group q (56 active, 8 guard lanes mirror lane 55,
// masked off shfl seams and stores). Jobs = 16*96 planes * 56 slabs = 86016
// waves -> 21504 blocks of 256 (4 jobs/block).

typedef float f4 __attribute__((ext_vector_type(4)));

#define LRN_H 224
#define LRN_W 224
#define LRN_WQ 56                    // float4 groups per row
#define LRN_R 4                      // output rows per job
#define LRN_IN (LRN_R + 4)           // 8 input rows per job
#define LRN_SLABS (LRN_H / LRN_R)    // 56
#define LRN_PLANE (LRN_H * LRN_W)

__global__ __launch_bounds__(256, 6) void LocalResponseNorm_17420387352942_kernel(
        const float* __restrict__ x, float* __restrict__ out) {
    const int q    = threadIdx.x & 63;
    const int wave = threadIdx.x >> 6;
    const int job  = blockIdx.x * 4 + wave;        // [0, 86016)
    const int plane = job / LRN_SLABS;
    const int slab  = job - plane * LRN_SLABS;
    const int h0    = slab * LRN_R;                // first output row

    const int qe = min(q, LRN_WQ - 1);             // guard lanes mirror lane 55
    const float* __restrict__ px = x   + (size_t)plane * LRN_PLANE + (qe << 2);
    float* __restrict__       po = out + (size_t)plane * LRN_PLANE + (qe << 2);

    const bool okL = (qe > 0);                     // left seam valid
    const bool okR = (qe < LRN_WQ - 1);            // right seam valid (also kills
                                                   // lane55<-guard-lane garbage)
    const bool wr  = (q < LRN_WQ);

    // ---- Load pass: 8 input rows h0-2 .. h0+5, one float4 per lane per row.
    // All 8 loads are independent and issue before any fold (8 KB/wave MLP).
    f4 X[LRN_IN];
#pragma unroll
    for (int r = 0; r < LRN_IN; ++r) {
        const int row = h0 + r - 2;
        const int rc  = min(max(row, 0), LRN_H - 1);   // clamped: in-bounds
        X[r] = *(const f4*)(px + rc * LRN_W);
    }

    // ---- Fold pass: square (masked), shfl neighbor taps, 5-tap horizontal
    // sums, scatter into the 4 output accumulators. Fully unrolled.
    f4 acc[LRN_R];
#pragma unroll
    for (int i = 0; i < LRN_R; ++i) acc[i] = (f4){0.f, 0.f, 0.f, 0.f};

#pragma unroll
    for (int r = 0; r < LRN_IN; ++r) {
        const int row = h0 + r - 2;
        const float mV = (row >= 0 && row < LRN_H) ? 1.0f : 0.0f;
        f4 sq = X[r] * X[r];
        sq *= mV;                                  // zero padded rows once

        float a  = __shfl_up(sq[2], 1);            // lane q-1: col 4q-2
        float b  = __shfl_up(sq[3], 1);            // lane q-1: col 4q-1
        float d0 = __shfl_down(sq[0], 1);          // lane q+1: col 4q+4
        float d1 = __shfl_down(sq[1], 1);          // lane q+1: col 4q+5
        a  = okL ? a  : 0.0f;
        b  = okL ? b  : 0.0f;
        d0 = okR ? d0 : 0.0f;
        d1 = okR ? d1 : 0.0f;

        float t = sq[1] + sq[2];                   // shared by all four windows
        f4 rs;
        rs[0] = a + b + sq[0] + t;                 // cols 4q-2 .. 4q+2
        rs[1] = b + sq[0] + t + sq[3];
        rs[2] = sq[0] + t + sq[3] + d0;
        rs[3] = t + sq[3] + d0 + d1;

        // rs of input row (h0+r-2) feeds output rows i in [r-4, r] ∩ [0, 4).
#pragma unroll
        for (int i = 0; i < LRN_R; ++i) {
            if (i <= r && r <= i + 4) acc[i] += rs;
        }
    }

    // ---- Epilogue: d^-0.75 via rsq + sqrt(rsq); centers are X[i+2].
#pragma unroll
    for (int i = 0; i < LRN_R; ++i) {
        f4 o;
#pragma unroll
        for (int j = 0; j < 4; ++j) {
            float d   = fmaf(1e-4f, acc[i][j], 2.0f);
            float rsq = __builtin_amdgcn_rsqf(d);              // d^-0.5
            o[j] = X[i + 2][j] * rsq * __builtin_amdgcn_sqrtf(rsq); // * d^-0.25
        }
        if (wr) __builtin_nontemporal_store(o, (f4*)(po + (h0 + i) * LRN_W));
    }
}

extern "C" void kernel_launch(void* const* d_in, const int* in_sizes, int n_in,
                              void* d_out, int out_size, void* d_ws, size_t ws_size,
                              hipStream_t stream) {
    const float* x = (const float*)d_in[0];
    float* out = (float*)d_out;
    // 16*96 planes * 56 slabs = 86016 jobs; 4 jobs (waves) per block.
    dim3 block(256, 1, 1);
    dim3 grid(86016 / 4, 1, 1);
    LocalResponseNorm_17420387352942_kernel<<<grid, block, 0, stream>>>(x, out);
}